// Round 1
// baseline (470.170 us; speedup 1.0000x reference)
//
#include <hip/hip_runtime.h>

// 3-level 2D Haar DWT, zero-pad mode, even sizes => pure 2x2 block transform.
// Band order in each yh tensor: (N, C, 3, H', W') with bands [lh, hl, hh].

__global__ __launch_bounds__(256) void haar_level_kernel(
    const float* __restrict__ in, float* __restrict__ ll_out,
    float* __restrict__ high_out, int NC, int Hin, int Win) {
  const int Hout = Hin >> 1;
  const int Wout = Win >> 1;
  const int wq = Wout >> 1;  // each thread produces 2 output columns

  long long tid = (long long)blockIdx.x * blockDim.x + threadIdx.x;
  long long total = (long long)NC * Hout * wq;
  if (tid >= total) return;

  int j2 = (int)(tid % wq);
  long long rest = tid / wq;
  int i  = (int)(rest % Hout);
  int nc = (int)(rest / Hout);

  const float4* r0 =
      reinterpret_cast<const float4*>(in + ((size_t)nc * Hin + 2 * i) * (size_t)Win) + j2;
  const float4* r1 =
      reinterpret_cast<const float4*>(in + ((size_t)nc * Hin + 2 * i + 1) * (size_t)Win) + j2;
  float4 a = *r0;  // row 2i,   cols 4*j2 .. 4*j2+3
  float4 b = *r1;  // row 2i+1, cols 4*j2 .. 4*j2+3

  // Row pass sums/diffs (width), then column pass (height).
  float s0 = a.x + a.y, d0 = a.x - a.y;  // row0, out col 2*j2
  float s1 = b.x + b.y, d1 = b.x - b.y;  // row1, out col 2*j2
  float s2 = a.z + a.w, d2 = a.z - a.w;  // row0, out col 2*j2+1
  float s3 = b.z + b.w, d3 = b.z - b.w;  // row1, out col 2*j2+1

  float2 ll = make_float2(0.5f * (s0 + s1), 0.5f * (s2 + s3));
  float2 lh = make_float2(0.5f * (s0 - s1), 0.5f * (s2 - s3));
  float2 hl = make_float2(0.5f * (d0 + d1), 0.5f * (d2 + d3));
  float2 hh = make_float2(0.5f * (d0 - d1), 0.5f * (d2 - d3));

  size_t ob = ((size_t)nc * Hout + i) * (size_t)Wout + 2 * j2;
  *reinterpret_cast<float2*>(ll_out + ob) = ll;

  size_t plane = (size_t)Hout * (size_t)Wout;
  size_t hb = ((size_t)nc * 3 * Hout + i) * (size_t)Wout + 2 * j2;
  *reinterpret_cast<float2*>(high_out + hb) = lh;
  *reinterpret_cast<float2*>(high_out + hb + plane) = hl;
  *reinterpret_cast<float2*>(high_out + hb + 2 * plane) = hh;
}

extern "C" void kernel_launch(void* const* d_in, const int* in_sizes, int n_in,
                              void* d_out, int out_size, void* d_ws, size_t ws_size,
                              hipStream_t stream) {
  const float* x = (const float*)d_in[0];
  float* out = (float*)d_out;

  // Output layout (flat, return order): ll(8,32,64,64), yh0(8,32,3,256,256),
  // yh1(8,32,3,128,128), yh2(8,32,3,64,64)
  float* ll_final = out;
  float* yh0 = out + 1048576;      // 8*32*64*64
  float* yh1 = out + 51380224;     // + 8*32*3*256*256
  float* yh2 = out + 63963136;     // + 8*32*3*128*128

  // Workspace: intermediate ll tensors
  float* ll1 = (float*)d_ws;       // 8*32*256*256 = 16,777,216 floats (64 MB)
  float* ll2 = ll1 + 16777216;     // 8*32*128*128 =  4,194,304 floats (16 MB)

  const int NC = 8 * 32;
  const int threads = 256;

  auto launch = [&](const float* in, float* ll, float* high, int Hin, int Win) {
    int Hout = Hin >> 1;
    int wq = Win >> 2;
    long long total = (long long)NC * Hout * wq;
    int blocks = (int)((total + threads - 1) / threads);
    haar_level_kernel<<<blocks, threads, 0, stream>>>(in, ll, high, NC, Hin, Win);
  };

  launch(x,   ll1,      yh0, 512, 512);
  launch(ll1, ll2,      yh1, 256, 256);
  launch(ll2, ll_final, yh2, 128, 128);
}

// Round 3
// 443.397 us; speedup vs baseline: 1.0604x; 1.0604x over previous
//
#include <hip/hip_runtime.h>

// 3-level 2D Haar DWT (zero-pad, even sizes => exact 2x2 block transform),
// fully fused: one kernel, one 128x128 input tile per 256-thread block.
// ll1 (64x64) and ll2 (32x32) intermediates live in LDS; yh0/yh1/yh2/ll
// are written straight to global. Band order per reference: [lh, hl, hh].
//
// Quad math (verified passing in round 1): for 2x2 block {a,b;c,d}:
//   row pass: s=a+b (lo), d=a-b (hi) per row; col pass:
//   ll=.5(s0+s1) lh=.5(s0-s1) hl=.5(d0+d1) hh=.5(d0-d1)

#define QUAD_MATH(A, Cc)                                     \
  float s0 = A.x + A.y, d0 = A.x - A.y;                      \
  float s1 = Cc.x + Cc.y, d1 = Cc.x - Cc.y;                  \
  float s2 = A.z + A.w, d2 = A.z - A.w;                      \
  float s3 = Cc.z + Cc.w, d3 = Cc.z - Cc.w;                  \
  float2 ll = make_float2(0.5f * (s0 + s1), 0.5f * (s2 + s3)); \
  float2 lh = make_float2(0.5f * (s0 - s1), 0.5f * (s2 - s3)); \
  float2 hl = make_float2(0.5f * (d0 + d1), 0.5f * (d2 + d3)); \
  float2 hh = make_float2(0.5f * (d0 - d1), 0.5f * (d2 - d3));

__global__ __launch_bounds__(256) void haar3_fused(
    const float* __restrict__ x, float* __restrict__ ll_out,
    float* __restrict__ yh0, float* __restrict__ yh1,
    float* __restrict__ yh2) {
  __shared__ float ll1[64 * 64];  // 16 KB
  __shared__ float ll2[32 * 32];  // 4 KB

  const int t = threadIdx.x;
  const int b = blockIdx.x;
  const int nc = b >> 4;        // 0..255
  const int tr = (b >> 2) & 3;  // tile row (of 4)
  const int tc = b & 3;         // tile col (of 4)

  // ---- Level 1: global 128x128 -> yh0 global + ll1 LDS (64x64) ----
  const float* xin = x + ((size_t)nc * 512 + (size_t)tr * 128) * 512 + tc * 128;
  float* y0 = yh0 + (size_t)nc * 3 * 65536 + (size_t)(tr * 64) * 256 + tc * 64;
#pragma unroll
  for (int k = 0; k < 8; ++k) {
    int p = t + (k << 8);   // 0..2047 pair index
    int pr = p >> 5;        // 0..63 output row
    int pc4 = p & 31;       // 0..31 float4 column
    float4 a = *(reinterpret_cast<const float4*>(xin + (2 * pr) * 512) + pc4);
    float4 c = *(reinterpret_cast<const float4*>(xin + (2 * pr + 1) * 512) + pc4);
    QUAD_MATH(a, c);
    *reinterpret_cast<float2*>(&ll1[pr * 64 + 2 * pc4]) = ll;
    float* o = y0 + pr * 256 + 2 * pc4;
    *reinterpret_cast<float2*>(o) = lh;
    *reinterpret_cast<float2*>(o + 65536) = hl;
    *reinterpret_cast<float2*>(o + 131072) = hh;
  }
  __syncthreads();

  // ---- Level 2: ll1 LDS -> yh1 global + ll2 LDS (32x32) ----
  float* y1 = yh1 + (size_t)nc * 3 * 16384 + (size_t)(tr * 32) * 128 + tc * 32;
#pragma unroll
  for (int k = 0; k < 2; ++k) {
    int p = t + (k << 8);  // 0..511 pair index
    int pr = p >> 4;       // 0..31 output row
    int pc = p & 15;       // 0..15 pair column
    float4 a = *reinterpret_cast<const float4*>(&ll1[(2 * pr) * 64 + 4 * pc]);
    float4 c = *reinterpret_cast<const float4*>(&ll1[(2 * pr + 1) * 64 + 4 * pc]);
    QUAD_MATH(a, c);
    *reinterpret_cast<float2*>(&ll2[pr * 32 + 2 * pc]) = ll;
    float* o = y1 + pr * 128 + 2 * pc;
    *reinterpret_cast<float2*>(o) = lh;
    *reinterpret_cast<float2*>(o + 16384) = hl;
    *reinterpret_cast<float2*>(o + 32768) = hh;
  }
  __syncthreads();

  // ---- Level 3: ll2 LDS -> yh2 global + ll_out global (16x16) ----
  if (t < 128) {
    int pr = t >> 3;  // 0..15 output row
    int pc = t & 7;   // 0..7 pair column
    float4 a = *reinterpret_cast<const float4*>(&ll2[(2 * pr) * 32 + 4 * pc]);
    float4 c = *reinterpret_cast<const float4*>(&ll2[(2 * pr + 1) * 32 + 4 * pc]);
    QUAD_MATH(a, c);
    float* ol = ll_out + (size_t)nc * 4096 + (size_t)(tr * 16 + pr) * 64 +
                tc * 16 + 2 * pc;
    *reinterpret_cast<float2*>(ol) = ll;
    float* o = yh2 + (size_t)nc * 3 * 4096 + (size_t)(tr * 16 + pr) * 64 +
               tc * 16 + 2 * pc;
    *reinterpret_cast<float2*>(o) = lh;
    *reinterpret_cast<float2*>(o + 4096) = hl;
    *reinterpret_cast<float2*>(o + 8192) = hh;
  }
}

extern "C" void kernel_launch(void* const* d_in, const int* in_sizes, int n_in,
                              void* d_out, int out_size, void* d_ws, size_t ws_size,
                              hipStream_t stream) {
  const float* x = (const float*)d_in[0];
  float* out = (float*)d_out;

  // Flat output layout (return order):
  // ll(8,32,64,64) | yh0(8,32,3,256,256) | yh1(8,32,3,128,128) | yh2(8,32,3,64,64)
  float* ll_final = out;
  float* yh0 = out + 1048576;
  float* yh1 = out + 51380224;
  float* yh2 = out + 63963136;

  // 256 (n*c) images x 16 tiles of 128x128 each
  haar3_fused<<<256 * 16, 256, 0, stream>>>(x, ll_final, yh0, yh1, yh2);
}